// Round 9
// baseline (432.397 us; speedup 1.0000x reference)
//
#include <hip/hip_runtime.h>
#include <cmath>

// Problem constants (fixed by setup_inputs)
static constexpr int SEQ = 1024;
static constexpr int DIM = 1024;
static constexpr int NH  = 16;
static constexpr int DH  = 64;   // head dim
static constexpr int WB  = 2;    // batch
static constexpr int ROWS = WB * SEQ;           // 2048
__device__ static constexpr double D_EPS = 1e-7;

typedef unsigned short ushort_t;
typedef __attribute__((ext_vector_type(8))) short short8v;   // 8 bf16 = 4 VGPR
typedef __attribute__((ext_vector_type(4))) float float4v;   // MFMA acc

// direct global->LDS async copy: one call moves 64 lanes x 16B; LDS dest is
// wave-uniform base; HW scatters lane i to base + i*16.
#define GLOAD_LDS(gp, lp)                                                   \
  __builtin_amdgcn_global_load_lds(                                         \
      (const __attribute__((address_space(1))) uint32_t*)(gp),              \
      (__attribute__((address_space(3))) uint32_t*)(lp), 16, 0, 0)

// ---------------- bf16 hi/lo split helpers ----------------
__device__ __forceinline__ uint32_t bf16_hi_bits(float f) {   // RNE to bf16
  uint32_t u = __float_as_uint(f);
  return (u + 0x7fffu + ((u >> 16) & 1u)) >> 16;
}

// MFMA-fragment-tiled address (16x16x32 shape) for element (row, col=k) of an
// [M x Kld] operand. Tile = 128 rows x 32 k = 4096 elems.
// In-tile: [sub(8)][lane(64)][j(8)], lane = q*16 + i, q = (col>>3)&3, i = row&15.
__device__ __forceinline__ size_t tiled_addr(int row, int col, int Kld) {
  return ((size_t)(row >> 7) * (Kld >> 5) + (col >> 5)) * 4096
       + (size_t)((((row >> 4) & 7) << 9) + (((col >> 3) & 3) << 7) + ((row & 15) << 3) + (col & 7));
}
__device__ __forceinline__ void store_hl(ushort_t* __restrict__ hi, ushort_t* __restrict__ lo,
                                         size_t addr, float f) {
  const uint32_t hb = bf16_hi_bits(f);
  hi[addr] = (ushort_t)hb;
  lo[addr] = (ushort_t)bf16_hi_bits(f - __uint_as_float(hb << 16));
}

// ---------------- reductions ----------------
__device__ __forceinline__ double wsum64(double v) {
#pragma unroll
  for (int m = 32; m >= 1; m >>= 1) v += __shfl_xor(v, m, 64);
  return v;
}

// ---------------- weight conversion body: fp32 [K x N] -> tiled hi/lo planes ----------------
__device__ __forceinline__ void conv_w_body(
    const float* __restrict__ W, ushort_t* __restrict__ hi, ushort_t* __restrict__ lo,
    int K, int N, int tid) {
  const int n = tid % N;
  const int k0 = (tid / N) << 3;
  uint32_t hw[4], lw[4];
#pragma unroll
  for (int rp = 0; rp < 4; rp++) {
    uint32_t h2[2], l2[2];
#pragma unroll
    for (int e = 0; e < 2; e++) {
      const float f = W[(size_t)(k0 + rp * 2 + e) * N + n];
      const uint32_t hb = bf16_hi_bits(f);
      h2[e] = hb;
      l2[e] = bf16_hi_bits(f - __uint_as_float(hb << 16));
    }
    hw[rp] = h2[0] | (h2[1] << 16);
    lw[rp] = l2[0] | (l2[1] << 16);
  }
  const size_t addr = tiled_addr(n, k0, K);   // multiple of 8
  *(uint4*)&hi[addr] = *(uint4*)hw;
  *(uint4*)&lo[addr] = *(uint4*)lw;
}

// merged conversion of Wq,Wk,Wv,Wo (512 blocks each) + W1 (2048 blocks)
__global__ __launch_bounds__(256) void conv_all_kernel(
    const float* __restrict__ Wq, const float* __restrict__ Wk,
    const float* __restrict__ Wv, const float* __restrict__ Wo,
    const float* __restrict__ W1,
    ushort_t* __restrict__ qkvo_hi, ushort_t* __restrict__ qkvo_lo,
    ushort_t* __restrict__ w1_hi, ushort_t* __restrict__ w1_lo) {
  const int blk = blockIdx.x;
  if (blk < 2048) {
    const int which = blk >> 9;
    const float* W = (which == 0) ? Wq : (which == 1) ? Wk : (which == 2) ? Wv : Wo;
    const size_t off = (size_t)which << 20;
    conv_w_body(W, qkvo_hi + off, qkvo_lo + off, DIM, DIM,
                (blk & 511) * 256 + threadIdx.x);
  } else {
    conv_w_body(W1, w1_hi, w1_lo, DIM, 4 * DIM, (blk - 2048) * 256 + threadIdx.x);
  }
}

// standalone conversion (W2, staged after Wo GEMM frees its units)
__global__ __launch_bounds__(256) void conv_w_kernel(
    const float* __restrict__ W, ushort_t* __restrict__ hi, ushort_t* __restrict__ lo,
    int K, int N) {
  conv_w_body(W, hi, lo, K, N, blockIdx.x * 256 + threadIdx.x);
}

// ---------------- LN chain device body: x row (fp32 regs) -> tiled hi/lo planes -------
__device__ __forceinline__ void ln_chain_body(
    const float xv[4], int row, double cc,
    const float* __restrict__ gamma, const float* __restrict__ beta,
    ushort_t* __restrict__ ohi, ushort_t* __restrict__ olo,
    double sh[3][4], int t) {
  double s0 = 0.0, s1 = 0.0;
#pragma unroll
  for (int i = 0; i < 4; i++) {
    s0 += (double)xv[i];
    s1 += (double)xv[i] * (double)xv[i];
  }
  s0 = wsum64(s0); s1 = wsum64(s1);
  const int wid = t >> 6, lane = t & 63;
  __syncthreads();
  if (lane == 0) { sh[0][wid] = s0; sh[1][wid] = s1; }
  __syncthreads();
  s0 = sh[0][0] + sh[0][1] + sh[0][2] + sh[0][3];
  s1 = sh[1][0] + sh[1][1] + sh[1][2] + sh[1][3];

  const double sqc = fmax(sqrt(cc), D_EPS);
  const double xn  = sqrt(s1);
  double a = 0.0;
  if (xn >= D_EPS) a = atanh(fmin(xn, 1.0 - D_EPS)) / sqc / fmax(xn, D_EPS);
  const double mu   = a * s0 / (double)DIM;
  const double var  = a * a * s1 / (double)DIM - mu * mu;
  const double invs = 1.0 / sqrt(var + 1e-6);

  double tv[4]; double s2 = 0.0;
#pragma unroll
  for (int i = 0; i < 4; i++) {
    const int col = t + 256 * i;
    tv[i] = (a * (double)xv[i] - mu) * invs * (double)gamma[col] + (double)beta[col];
    s2 += tv[i] * tv[i];
  }
  s2 = wsum64(s2);
  __syncthreads();
  if (lane == 0) sh[0][wid] = s2;
  __syncthreads();
  s2 = sh[0][0] + sh[0][1] + sh[0][2] + sh[0][3];

  const double tn = sqrt(s2);
  double C = 0.0;
  if (tn >= D_EPS) {
    const double safe_t = fmax(tn, D_EPS);
    const double mag2 = tanh(sqc * safe_t) / sqc;   // expmap0 magnitude
    const double en = mag2 * (tn / safe_t);         // ||e|| analytic
    const double pn = fmax(en, D_EPS);
    const double f  = (pn >= 1.0) ? (1.0 - D_EPS) / pn : 1.0;   // project
    const double yn = en * f;
    if (yn >= D_EPS) {
      const double mag3 = atanh(fmin(yn, 1.0 - D_EPS)) / sqc;   // logmap0
      C = (mag2 / safe_t) * f * (mag3 / fmax(yn, D_EPS));
    }
  }
#pragma unroll
  for (int i = 0; i < 4; i++) {
    const int col = t + 256 * i;
    store_hl(ohi, olo, tiled_addr(row, col, DIM), (float)(tv[i] * C));
  }
}

// ---------------- tangent-space layernorm chain kernel (LN1) ----------------
__global__ __launch_bounds__(256) void ln_tan_kernel(
    const float* __restrict__ xin, const float* __restrict__ cb,
    const float* __restrict__ gamma, const float* __restrict__ beta,
    ushort_t* __restrict__ ohi, ushort_t* __restrict__ olo) {
  __shared__ double sh[3][4];
  const int row = blockIdx.x;
  const int b = row / SEQ;
  const float* xr = xin + (size_t)row * DIM;
  const int t = threadIdx.x;
  float xv[4];
#pragma unroll
  for (int i = 0; i < 4; i++) xv[i] = xr[t + 256 * i];
  ln_chain_body(xv, row, (double)cb[b], gamma, beta, ohi, olo, sh, t);
}

// ------- mobius core: given row sums, produce Pd,Qd -------
__device__ __forceinline__ void mobius_coef(
    double sx2, double st2, double sxt, double cc, double& Pd, double& Qd) {
  const double sqc = fmax(sqrt(cc), D_EPS);
  const double tn = sqrt(st2);
  double s = 0.0;
  if (tn >= D_EPS) {
    const double safe = fmax(tn, D_EPS);
    const double mag = tanh(sqc * safe) / sqc;      // expmap0
    const double en = mag * (tn / safe);
    const double pn = fmax(en, D_EPS);
    const double f  = (pn >= 1.0) ? (1.0 - D_EPS) / pn : 1.0;  // project
    s = (mag / safe) * f;                            // y_i = s * t_i
  }
  const double x2 = sx2, y2 = s * s * st2, xy = s * sxt;
  const double P   = 1.0 + 2.0 * cc * xy + cc * y2;
  const double Q   = 1.0 - cc * x2;
  const double den = fmax(1.0 + 2.0 * cc * xy + cc * cc * x2 * y2, D_EPS);
  const double num2 = P * P * x2 + Q * Q * y2 + 2.0 * P * Q * xy;
  const double rn  = sqrt(fmax(num2, 0.0)) / den;
  const double pn2 = fmax(rn, D_EPS);
  const double pf  = (pn2 >= 1.0) ? (1.0 - D_EPS) / pn2 : 1.0;  // project
  Pd = (P / den) * pf;
  Qd = (Q / den) * pf * s;
}

// ------- out = mobius_add(xb, expmap0(p0+p1+p2+p3+bias, c), c) -------
// NOTE: may be called with out == xb (each thread reads its cols before writing).
__global__ __launch_bounds__(256) void expmobius_parts4_kernel(
    const float* __restrict__ xb,
    const float* __restrict__ p0, const float* __restrict__ p1,
    const float* __restrict__ p2, const float* __restrict__ p3,
    const float* __restrict__ bias, const float* __restrict__ cb,
    float* __restrict__ out) {
  __shared__ double sh[3][4];
  const int row = blockIdx.x;
  const int b = row / SEQ;
  const size_t ro = (size_t)row * DIM;
  const int t = threadIdx.x;
  float xv[4];
  double tv[4];
  double sx2 = 0.0, st2 = 0.0, sxt = 0.0;
#pragma unroll
  for (int i = 0; i < 4; i++) {
    const int col = t + 256 * i;
    xv[i] = xb[ro + col];
    tv[i] = (double)p0[ro + col] + (double)p1[ro + col] +
            (double)p2[ro + col] + (double)p3[ro + col] + (double)bias[col];
    sx2 += (double)xv[i] * (double)xv[i];
    st2 += tv[i] * tv[i];
    sxt += (double)xv[i] * tv[i];
  }
  sx2 = wsum64(sx2); st2 = wsum64(st2); sxt = wsum64(sxt);
  const int wid = t >> 6, lane = t & 63;
  if (lane == 0) { sh[0][wid] = sx2; sh[1][wid] = st2; sh[2][wid] = sxt; }
  __syncthreads();
  sx2 = sh[0][0] + sh[0][1] + sh[0][2] + sh[0][3];
  st2 = sh[1][0] + sh[1][1] + sh[1][2] + sh[1][3];
  sxt = sh[2][0] + sh[2][1] + sh[2][2] + sh[2][3];
  double Pd, Qd;
  mobius_coef(sx2, st2, sxt, (double)cb[b], Pd, Qd);
#pragma unroll
  for (int i = 0; i < 4; i++)
    out[ro + t + 256 * i] = (float)(Pd * (double)xv[i] + Qd * tv[i]);
}

// ------- fused: x_att = mobius_add(x, expmap0(parts+bias)); t2P = LN-chain(x_att) -------
__global__ __launch_bounds__(256) void expmobius_ln_kernel(
    const float* __restrict__ xb,
    const float* __restrict__ p0, const float* __restrict__ p1,
    const float* __restrict__ p2, const float* __restrict__ p3,
    const float* __restrict__ bias, const float* __restrict__ cb,
    const float* __restrict__ gamma, const float* __restrict__ beta,
    float* __restrict__ out, ushort_t* __restrict__ ohi, ushort_t* __restrict__ olo) {
  __shared__ double sh[3][4];
  const int row = blockIdx.x;
  const int b = row / SEQ;
  const size_t ro = (size_t)row * DIM;
  const int t = threadIdx.x;
  float xv[4];
  double tv[4];
  double sx2 = 0.0, st2 = 0.0, sxt = 0.0;
#pragma unroll
  for (int i = 0; i < 4; i++) {
    const int col = t + 256 * i;
    xv[i] = xb[ro + col];
    tv[i] = (double)p0[ro + col] + (double)p1[ro + col] +
            (double)p2[ro + col] + (double)p3[ro + col] + (double)bias[col];
    sx2 += (double)xv[i] * (double)xv[i];
    st2 += tv[i] * tv[i];
    sxt += (double)xv[i] * tv[i];
  }
  sx2 = wsum64(sx2); st2 = wsum64(st2); sxt = wsum64(sxt);
  const int wid = t >> 6, lane = t & 63;
  if (lane == 0) { sh[0][wid] = sx2; sh[1][wid] = st2; sh[2][wid] = sxt; }
  __syncthreads();
  sx2 = sh[0][0] + sh[0][1] + sh[0][2] + sh[0][3];
  st2 = sh[1][0] + sh[1][1] + sh[1][2] + sh[1][3];
  sxt = sh[2][0] + sh[2][1] + sh[2][2] + sh[2][3];
  const double cc = (double)cb[b];
  double Pd, Qd;
  mobius_coef(sx2, st2, sxt, cc, Pd, Qd);
  float ov[4];
#pragma unroll
  for (int i = 0; i < 4; i++) {
    ov[i] = (float)(Pd * (double)xv[i] + Qd * tv[i]);   // fp32-rounded x_att
    out[ro + t + 256 * i] = ov[i];
  }
  // LN2 chain on the fp32-rounded x_att (bit-matches the unfused two-kernel path)
  ln_chain_body(ov, row, cc, gamma, beta, ohi, olo, sh, t);
}

// ---------------- RoPE + expmap0 per head, in place on q and k ----------------
// Also emits per-(row,head) squared norms of the STORED fp32 outputs (fp64).
__global__ __launch_bounds__(256) void rope_expmap_kernel(
    float* __restrict__ q, float* __restrict__ k,
    const float* __restrict__ freqs, const float* __restrict__ cb,
    double* __restrict__ q2d, double* __restrict__ k2d) {
  const int row = blockIdx.x;           // b*SEQ + n
  const int b = row / SEQ, n = row % SEQ;
  const int t = threadIdx.x;
  const int h = t >> 4, j = t & 15;
  const int p1 = j, p2 = j + 16;        // pair indices in [0,32)
  const double f1 = (double)freqs[n * (DH / 2) + p1];
  const double f2 = (double)freqs[n * (DH / 2) + p2];
  const double c1 = cos(f1), s1 = sin(f1);
  const double c2 = cos(f2), s2 = sin(f2);
  const double cc  = (double)cb[b];
  const double sqc = fmax(sqrt(cc), D_EPS);
  const size_t base = (size_t)row * DIM + (size_t)h * DH;
  float* arrs[2] = {q, k};
  double* outs[2] = {q2d, k2d};
#pragma unroll
  for (int a = 0; a < 2; a++) {
    float* p = arrs[a] + base;
    const double xr1 = p[p1], xi1 = p[p1 + 32];
    const double xr2 = p[p2], xi2 = p[p2 + 32];
    const double r1 = xr1 * c1 - xi1 * s1, i1 = xr1 * s1 + xi1 * c1;
    const double r2 = xr2 * c2 - xi2 * s2, i2 = xr2 * s2 + xi2 * c2;
    double nrm2 = r1 * r1 + i1 * i1 + r2 * r2 + i2 * i2;
#pragma unroll
    for (int m = 8; m >= 1; m >>= 1) nrm2 += __shfl_xor(nrm2, m, 16);
    const double vn = sqrt(nrm2);
    double sc = 0.0;
    if (vn >= D_EPS) {
      const double safe = fmax(vn, D_EPS);
      const double mag = tanh(sqc * safe) / sqc;
      const double en = mag * (vn / safe);
      const double pn = fmax(en, D_EPS);
      const double f  = (pn >= 1.0) ? (1.0 - D_EPS) / pn : 1.0;
      sc = (mag / safe) * f;
    }
    const float o1 = (float)(r1 * sc), o2 = (float)(i1 * sc);
    const float o3 = (float)(r2 * sc), o4 = (float)(i2 * sc);
    p[p1] = o1; p[p1 + 32] = o2;
    p[p2] = o3; p[p2 + 32] = o4;
    // exact fp64 sum of squares of the STORED fp32 values
    double s2 = (double)o1 * o1 + (double)o2 * o2 + (double)o3 * o3 + (double)o4 * o4;
#pragma unroll
    for (int m = 8; m >= 1; m >>= 1) s2 += __shfl_xor(s2, m, 16);
    if (j == 0) outs[a][row * NH + h] = s2;
  }
}

// ---------------- sliding-window Poincare attention (tiled hi/lo output) ----------------
// 32 lanes per (b,h,n); lane w handles key n-31+w. PV: lane w owns dims 2w,2w+1.
__global__ __launch_bounds__(256) void attn_kernel(
    const float* __restrict__ qh, const float* __restrict__ kh,
    const float* __restrict__ v, const float* __restrict__ cb,
    const float* __restrict__ geo,
    const double* __restrict__ q2d, const double* __restrict__ k2d,
    ushort_t* __restrict__ ohi, ushort_t* __restrict__ olo) {
  __shared__ __align__(16) float qs[8][DH];
  const int g = threadIdx.x >> 5;       // group in block: 0..7
  const int w = threadIdx.x & 31;       // lane in group
  const int gid = blockIdx.x * 8 + g;   // (b*NH + h)*SEQ + n
  const int n = gid & (SEQ - 1);
  const int bh = gid >> 10;
  const int h = bh & (NH - 1);
  const int b = bh >> 4;
  const int row = b * SEQ + n;
  const size_t qbase = (size_t)row * DIM + (size_t)h * DH;
  qs[g][w] = qh[qbase + w];
  qs[g][w + 32] = qh[qbase + w + 32];
  __syncthreads();

  const double cc  = (double)cb[b];
  const double sqc = fmax(sqrt(cc), D_EPS);
  const double a2 = q2d[row * NH + h];

  const int msrc = n - 31 + w;
  double y2 = 0.0, qy = 0.0;
  if (msrc >= 0) {
    const int krow = b * SEQ + msrc;
    y2 = k2d[krow * NH + h];
    const float4* kr4 = (const float4*)(kh + (size_t)krow * DIM + (size_t)h * DH);
    const float4* qs4 = (const float4*)qs[g];
#pragma unroll
    for (int d = 0; d < 16; d++) {
      const float4 kv = kr4[d];
      const float4 qv = qs4[d];
      qy += (double)qv.x * (double)kv.x;
      qy += (double)qv.y * (double)kv.y;
      qy += (double)qv.z * (double)kv.z;
      qy += (double)qv.w * (double)kv.w;
    }
  }
  const double ay = -qy;  // mobius_add(-q, k)
  const double P = 1.0 + 2.0 * cc * ay + cc * y2;
  const double Q = 1.0 - cc * a2;
  const double den = fmax(1.0 + 2.0 * cc * ay + cc * cc * a2 * y2, D_EPS);
  const double num2 = P * P * a2 + Q * Q * y2 + 2.0 * P * Q * ay;
  const double rn = sqrt(fmax(num2, 0.0)) / den;
  const double pn = fmax(rn, D_EPS);
  const double addn = (pn >= 1.0) ? (1.0 - D_EPS) * (rn / pn) : rn;  // project
  const double arg = fmin(sqc * addn, 1.0 - D_EPS);
  const double dist = 2.0 * atanh(arg) / sqc;
  const double logit = -(double)geo[h] * dist;

  double mx = logit;
#pragma unroll
  for (int m = 16; m >= 1; m >>= 1) mx = fmax(mx, __shfl_xor(mx, m, 32));
  const double e = exp(logit - mx);
  double se = e;
#pragma unroll
  for (int m = 16; m >= 1; m >>= 1) se += __shfl_xor(se, m, 32);
  const double p = e / se;

  // PV: lane w accumulates output dims 2w, 2w+1 (float2 loads)
  double acc1 = 0.0, acc2 = 0.0;
  for (int wp = 0; wp < 32; wp++) {
    const double pw = __shfl(p, wp, 32);
    const int mp = n - 31 + wp;
    if (mp >= 0) {
      const float2 vv = ((const float2*)(v + ((size_t)(b * SEQ + mp)) * DIM + (size_t)h * DH))[w];
      acc1 += pw * (double)vv.x;
      acc2 += pw * (double)vv.y;
    }
  }
  const int col = h * DH + 2 * w;
  store_hl(ohi, olo, tiled_addr(row, col, DIM), (float)acc1);
  store_hl(ohi, olo, tiled_addr(row, col + 1, DIM), (float)acc2);
}

// ---------------- epilogue helper ----------------
__device__ __forceinline__ float gelu_tanh(float x) {
  const float x3 = x * x * x;
  return 0.5f * x * (1.0f + tanhf(0.7978845608028654f * (x + 0.044715f * x3)));
}

// ===== bf16x3 MFMA GEMM body: 128x128 tile, 256 thr (4 waves), BK=32 =====
// 16x16x32 MFMA, wave-tile 64x64. A,B: tiled hi/lo planes in fragment order.
// Staging via global_load_lds (m97 structure): zero staging VGPRs, no ds_writes.
// EPI: 0 = +bias fp32 out; 1 = +bias gelu tiled out; 2 = fp32 partial (no bias).
template <int EPI>
__device__ __forceinline__ void mfma_gemm_body(
    const ushort_t* __restrict__ Ahi, const ushort_t* __restrict__ Alo, int Kld,
    const ushort_t* __restrict__ Bhi, const ushort_t* __restrict__ Blo, int KB,
    const float* __restrict__ bias, float* __restrict__ Cf,
    ushort_t* __restrict__ Chi, ushort_t* __restrict__ Clo, int KldOut,
    int N, int k0, int klen, int m0, int n0) {
  __shared__ __align__(16) ushort_t AsH[4096], AsL[4096], BsH[4096], BsL[4096];
  const int t = threadIdx.x;
  const int lane = t & 63, wave = t >> 6;
  const int wm = (wave >> 1) << 6, wn = (wave & 1) << 6;   // 64x64 per wave
  const size_t abase = (size_t)(m0 >> 7) * (Kld >> 5) * 4096;
  const size_t bbase = (size_t)(n0 >> 7) * (KB >> 5) * 4096;

  float4v acc[4][4];
#pragma unroll
  for (int i = 0; i < 4; i++)
#pragma unroll
    for (int j = 0; j < 4; j++) acc[i][j] = (float4v){0.f, 0.f, 0.f, 0.f};

  for (int kt = 0; kt < klen; kt += 32) {
    const size_t at = abase + (size_t)((k0 + kt) >> 5) * 4096;
    const size_t bt = bbase + (size_t)((k0 + kt) >> 5) * 4096;
    __syncthreads();                   // prev compute done, LDS reusable
    // stage 4 plane-tiles of 8 KB: 2 rounds x (4 waves x 1 KB DMA) each
#pragma unroll
    for (int r = 0; r < 2; r++) {
      const int go = (r << 11) + (t << 3);          // per-lane ushort offset
      const int lo = (r << 11) + (wave << 9);       // wave-uniform LDS base
      GLOAD_LDS(Ahi + at + go, AsH + lo);
      GLOAD_LDS(Alo + at + go, AsL + lo);
      GLOAD_LDS(Bhi + bt + go, BsH + lo);
      GLOAD_LDS(Blo + bt + go, BsL + lo);
    }
    __syncthreads();                   // drains vmcnt: tile resident
    // compute: 48 MFMAs (bf16x3: HH + HL + LH)
    short8v aH[4], aL[4];
    const int ams = wm >> 4;
#pragma unroll
    for (int im = 0; im < 4; im++) {
      const int off = ((((ams + im) << 6) + lane) << 3);
      aH[im] = *(const short8v*)&AsH[off];
      aL[im] = *(const short8v*)&AsL[off];
    }
    const int bns = wn >> 4;
#pragma unroll
    for (int in_ = 0; in_ < 4; in_++) {
      const int off = ((((bns + in_) << 6) + lane) << 3);
      const short8v bH = *(const short8v*)&BsH[off];
      const short8v bL = *(const short8v*)&BsL[off];
#pragma unroll
      for (int im = 0; im < 4; im++) {
        acc[im][in_] = __builtin_amdgcn_mfma_f32_16x16x32_bf16(aH[im], bH, acc[im][in_], 0, 0, 0);
        acc[im][in_] = __builtin_amdgcn_mfma_f32_16x16x32_bf16(aH[im], bL, acc[im][in_], 0, 0, 0);
        acc[im][in_] = __builtin_amdgcn_mfma_f32_16x16x32_bf16(aL[im], bH, acc[im][in_], 0, 0, 0);
      }
    }
  }
  // epilogue: C/D layout col = lane&15, row = (lane>>4)*4 + r
  const int cq = lane >> 4, ci = lane & 15;
#pragma unroll
  for (int im = 0; im < 4; im++) {
    const int row = m0 + wm + im * 16 + cq * 4;
#pragma unroll
    for (int in_ = 0; in_ < 4; in_++) {
      const int col = n0 + wn + in_ * 16 + ci;
      if (EPI == 2) {
#pragma unroll
        for (int r = 0; r < 4; r++) Cf[(size_t)(row + r) * N + col] = acc[im][in_][r];
      } else if (EPI == 0) {
        const float bv_ = bias[col];
#pragma unroll
        for (int r = 0; r < 4; r++) Cf[(size_t)(row + r) * N + col] = acc[im][in_][r] + bv_;
      } else {
        const float bv_ = bias[col];
#pragma unroll
        for (int r = 0; r < 4; r++)
          store_hl(Chi, Clo, tiled_addr(row + r, col, KldOut),
                   gelu_tanh(acc[im][in_][r] + bv_));
      }
    }
  }
}

// fused QKV: blockIdx.x = which*8 + ntile
__global__ __launch_bounds__(256) void qkv_mfma(
    const ushort_t* __restrict__ Ahi, const ushort_t* __restrict__ Alo,
    const ushort_t* __restrict__ Whi, const ushort_t* __restrict__ Wlo,
    const float* __restrict__ bq, const float* __restrict__ bk, const float* __restrict__ bv,
    float* __restrict__ Cq, float* __restrict__ Ck, float* __restrict__ Cv) {
  const int which = blockIdx.x >> 3;
  const int n0 = (blockIdx.x & 7) << 7;
  const size_t woff = (size_t)which << 20;
  const float* bias = (which == 0) ? bq : (which == 1) ? bk : bv;
  float* C = (which == 0) ? Cq : (which == 1) ? Ck : Cv;
  mfma_gemm_body<0>(Ahi, Alo, DIM, Whi + woff, Wlo + woff, DIM, bias, C,
                    nullptr, nullptr, 0, DIM, 0, DIM, blockIdx.y << 7, n0);
}

// FFN up + gelu, tiled hi/lo hidden output
__global__ __launch_bounds__(256) void ffn_up_mfma(
    const ushort_t* __restrict__ Ahi, const ushort_t* __restrict__ Alo,
    const ushort_t* __restrict__ W1hi, const ushort_t* __restrict__ W1lo,
    const float* __restrict__ b1, ushort_t* __restrict__ Hhi, ushort_t* __restrict__ Hlo) {
  mfma_gemm_body<1>(Ahi, Alo, DIM, W1hi, W1lo, DIM, b1, nullptr, Hhi, Hlo, 4 * DIM,
                    4 * DIM, 0, DIM, blockIdx.y << 7, blockIdx.x << 7);
}

// split-K partial GEMM: blockIdx.z picks k-chunk and partial buffer
__global__ __launch_bounds__(256) void gemm_splitk_mfma(
    const ushort_t* __restrict__ Ahi, const ushort_t* __restrict__ Alo, int Kld,
    const ushort_t* __restrict__ Bhi, const ushort_t* __restrict__ Blo, int KB,
    float* __restrict__ C0, float* __restrict__ C1,
    float* __restrict__ C2, float* __restrict__ C3, int N, int klen) {
  const int z = blockIdx.z;
  float* C = (z == 0) ? C0 : (z == 1) ? C1 : (z == 2) ? C2 : C3;
  mfma_gemm_body<2>(Ahi, Alo, Kld, Bhi, Blo, KB, nullptr, C, nullptr, nullptr, 0,
                    N, z * klen, klen, blockIdx.y << 7, blockIdx.x << 7);
}

extern "C" void kernel_launch(void* const* d_in, const int* in_sizes, int n_in,
                              void* d_out, int out_size, void* d_ws, size_t ws_size,
                              hipStream_t stream) {
  const float* x     = (const float*)d_in[0];
  const float* freqs = (const float*)d_in[1];
  const float* c     = (const float*)d_in[2];
  const float* Wq = (const float*)d_in[3];  const float* bq = (const float*)d_in[4];
  const float* Wk = (const float*)d_in[5];  const float* bk = (const float*)d_in[6];
  const float* Wv = (const float*)d_in[7];  const float* bv = (const float*)d_in[8];
  const float* Wo = (const float*)d_in[9];  const float* bo = (const float*)d_in[10];
  const float* W1 = (const float*)d_in[11]; const float* b1 = (const float*)d_in[12];
  const float* W2 = (const float*)d_in[13]; const float* b2 = (const float*)d_in[14];
  const float* g1 = (const float*)d_in[15]; const float* be1 = (const float*)d_in[16];
  const float* g2 = (const float*)d_in[17]; const float* be2 = (const float*)d_in[18];
  const float* geo = (const float*)d_in[19];
  float* out = (float*)d_out;
  float* ws = (float*)d_ws;

  const size_t SZ = (size_t)ROWS * DIM;       // 2M floats per unit (8 MB) = 4M ushorts
  const size_t PL = SZ;                       // ushorts per activation plane (half unit)
  const uint32_t M1 = 1u << 20;               // ushorts per 1024x1024 weight plane
  auto us = [&](int i) { return (ushort_t*)(ws + (size_t)i * SZ); };

  // Unit plan (x_att lives in d_out) — audited R5 plan:
  // u0: x_tanP hi+lo  -> Wo part0 -> h1 hi (low half)
  // u1: qb            -> Wo part1 -> h1 hi (high half)
  // u2: kb            -> Wo part2 -> h1 lo (low half)
  // u3: vb            -> Wo part3 -> h1 lo (high half)
  // u4: attP hi+lo    -> t2P hi+lo -> FFN part0
  // u5: Wq/Wk/Wv/Wo hi planes -> W2 hi      u6: same, lo planes -> W2 lo
  // u7: W1 hi -> FFN part1    u8: W1 lo -> FFN part2
  // u9: q2/k2 norm tables (steps 3-4) -> FFN part3 (step 9+)
  ushort_t* xt_hi = us(0);           ushort_t* xt_lo = us(0) + PL;
  float* qb = ws + 1 * SZ; float* kb = ws + 2 * SZ; float* vb = ws + 3 * SZ;
  ushort_t* at_hi = us(4);           ushort_t* at_lo = us(4) + PL;
  ushort_t* qkvo_hi = us(5);         ushort_t* qkvo_lo = us(6);
  ushort_t* w1_hi = us(7);           ushort_t* w1_lo = us(8);
  ushort_t* w2_hi = us(5);           ushort_t* w2_lo = us(6);
  ushort_t* t2_hi = us(4);           ushort_t* t2_lo = us(4) + PL;
  ushort_t* h1_hi = us(0);           ushort_t* h1_lo = us(2);   // each spans 2 units
  double* q2d = (double*)(ws + 9 * SZ);        // ROWS*NH doubles (256 KB)
  double* k2d = q2d + (size_t)ROWS * NH;
  float* x_att = out;

  // 0. merged weight conversion (QKV+Wo -> u5/u6, W1 -> u7/u8)
  conv_all_kernel<<<4096, 256, 0, stream>>>(
      Wq, Wk, Wv, Wo, W1, qkvo_hi, qkvo_lo, w1_hi, w1_lo);
  // 1. tangent LN1 -> tiled planes (u0)
  ln_tan_kernel<<<ROWS, 256, 0, stream>>>(x, c, g1, be1, xt_hi, xt_lo);
  // 2. fused QKV (384 blocks)
  qkv_mfma<<<dim3(24, ROWS / 128), 256, 0, stream>>>(
      xt_hi, xt_lo, qkvo_hi, qkvo_lo, bq, bk, bv, qb, kb, vb);
  // 3. RoPE + expmap0 (q,k in place) + norm tables -> u9
  rope_expmap_kernel<<<ROWS, 256, 0, stream>>>(qb, kb, freqs, c, q2d, k2d);
  // 4. sliding-window Poincare attention -> tiled planes (u4)
  attn_kernel<<<WB * NH * SEQ / 8, 256, 0, stream>>>(
      qb, kb, vb, c, geo, q2d, k2d, at_hi, at_lo);
  // 5. output projection, split-K=4 -> partials u0..u3 (klen=256)
  gemm_splitk_mfma<<<dim3(DIM / 128, ROWS / 128, 4), 256, 0, stream>>>(
      at_hi, at_lo, DIM, qkvo_hi + 3 * M1, qkvo_lo + 3 * M1, DIM,
      ws + 0 * SZ, ws + 1 * SZ, ws + 2 * SZ, ws + 3 * SZ, DIM, DIM / 4);
  // 5b. W2 conversion into freed u5/u6
  conv_w_kernel<<<2048, 256, 0, stream>>>(W2, w2_hi, w2_lo, 4 * DIM, DIM);
  // 6+7. fused: x_att = mobius(...), t2P = LN2-chain(x_att) -> u4
  expmobius_ln_kernel<<<ROWS, 256, 0, stream>>>(
      x, ws + 0 * SZ, ws + 1 * SZ, ws + 2 * SZ, ws + 3 * SZ, bo, c,
      g2, be2, x_att, t2_hi, t2_lo);
  // 8. FFN up + gelu -> tiled hidden planes (u0-u3)
  ffn_up_mfma<<<dim3(4 * DIM / 128, ROWS / 128), 256, 0, stream>>>(
      t2_hi, t2_lo, w1_hi, w1_lo, b1, h1_hi, h1_lo);
  // 9. FFN down, split-K=4 -> partials u4,u7,u8,u9 (klen=1024; u9 norm tables dead)
  gemm_splitk_mfma<<<dim3(DIM / 128, ROWS / 128, 4), 256, 0, stream>>>(
      h1_hi, h1_lo, 4 * DIM, w2_hi, w2_lo, 4 * DIM,
      ws + 4 * SZ, ws + 7 * SZ, ws + 8 * SZ, ws + 9 * SZ, DIM, DIM);
  // 10. out = mobius_add(x_att, expmap0(sum(partials)+b2))  [out == x_att: safe]
  expmobius_parts4_kernel<<<ROWS, 256, 0, stream>>>(
      x_att, ws + 4 * SZ, ws + 7 * SZ, ws + 8 * SZ, ws + 9 * SZ, b2, c, out);
  (void)in_sizes; (void)n_in; (void)out_size; (void)ws_size;
}

// Round 10
// 409.788 us; speedup vs baseline: 1.0552x; 1.0552x over previous
//
#include <hip/hip_runtime.h>
#include <cmath>

// Problem constants (fixed by setup_inputs)
static constexpr int SEQ = 1024;
static constexpr int DIM = 1024;
static constexpr int NH  = 16;
static constexpr int DH  = 64;   // head dim
static constexpr int WB  = 2;    // batch
static constexpr int ROWS = WB * SEQ;           // 2048
__device__ static constexpr double D_EPS = 1e-7;

typedef unsigned short ushort_t;
typedef __attribute__((ext_vector_type(8))) short short8v;   // 8 bf16 = 4 VGPR
typedef __attribute__((ext_vector_type(4))) float float4v;   // MFMA acc

// direct global->LDS async copy: one call moves 64 lanes x 16B; LDS dest is
// wave-uniform base; HW scatters lane i to base + i*16.
#define GLOAD_LDS(gp, lp)                                                   \
  __builtin_amdgcn_global_load_lds(                                         \
      (const __attribute__((address_space(1))) uint32_t*)(gp),              \
      (__attribute__((address_space(3))) uint32_t*)(lp), 16, 0, 0)

// ---------------- bf16 hi/lo split helpers ----------------
__device__ __forceinline__ uint32_t bf16_hi_bits(float f) {   // RNE to bf16
  uint32_t u = __float_as_uint(f);
  return (u + 0x7fffu + ((u >> 16) & 1u)) >> 16;
}

// MFMA-fragment-tiled address (16x16x32 shape) for element (row, col=k) of an
// [M x Kld] operand. Tile = 128 rows x 32 k = 4096 elems.
// In-tile: [sub(8)][lane(64)][j(8)], lane = q*16 + i, q = (col>>3)&3, i = row&15.
__device__ __forceinline__ size_t tiled_addr(int row, int col, int Kld) {
  return ((size_t)(row >> 7) * (Kld >> 5) + (col >> 5)) * 4096
       + (size_t)((((row >> 4) & 7) << 9) + (((col >> 3) & 3) << 7) + ((row & 15) << 3) + (col & 7));
}
__device__ __forceinline__ void store_hl(ushort_t* __restrict__ hi, ushort_t* __restrict__ lo,
                                         size_t addr, float f) {
  const uint32_t hb = bf16_hi_bits(f);
  hi[addr] = (ushort_t)hb;
  lo[addr] = (ushort_t)bf16_hi_bits(f - __uint_as_float(hb << 16));
}

// ---------------- reductions ----------------
__device__ __forceinline__ double wsum64(double v) {
#pragma unroll
  for (int m = 32; m >= 1; m >>= 1) v += __shfl_xor(v, m, 64);
  return v;
}

// ---------------- weight conversion body: fp32 [K x N] -> tiled hi/lo planes ----------------
__device__ __forceinline__ void conv_w_body(
    const float* __restrict__ W, ushort_t* __restrict__ hi, ushort_t* __restrict__ lo,
    int K, int N, int tid) {
  const int n = tid % N;
  const int k0 = (tid / N) << 3;
  uint32_t hw[4], lw[4];
#pragma unroll
  for (int rp = 0; rp < 4; rp++) {
    uint32_t h2[2], l2[2];
#pragma unroll
    for (int e = 0; e < 2; e++) {
      const float f = W[(size_t)(k0 + rp * 2 + e) * N + n];
      const uint32_t hb = bf16_hi_bits(f);
      h2[e] = hb;
      l2[e] = bf16_hi_bits(f - __uint_as_float(hb << 16));
    }
    hw[rp] = h2[0] | (h2[1] << 16);
    lw[rp] = l2[0] | (l2[1] << 16);
  }
  const size_t addr = tiled_addr(n, k0, K);   // multiple of 8
  *(uint4*)&hi[addr] = *(uint4*)hw;
  *(uint4*)&lo[addr] = *(uint4*)lw;
}

// merged conversion of Wq,Wk,Wv,Wo (512 blocks each) + W1 (2048 blocks)
__global__ __launch_bounds__(256) void conv_all_kernel(
    const float* __restrict__ Wq, const float* __restrict__ Wk,
    const float* __restrict__ Wv, const float* __restrict__ Wo,
    const float* __restrict__ W1,
    ushort_t* __restrict__ qkvo_hi, ushort_t* __restrict__ qkvo_lo,
    ushort_t* __restrict__ w1_hi, ushort_t* __restrict__ w1_lo) {
  const int blk = blockIdx.x;
  if (blk < 2048) {
    const int which = blk >> 9;
    const float* W = (which == 0) ? Wq : (which == 1) ? Wk : (which == 2) ? Wv : Wo;
    const size_t off = (size_t)which << 20;
    conv_w_body(W, qkvo_hi + off, qkvo_lo + off, DIM, DIM,
                (blk & 511) * 256 + threadIdx.x);
  } else {
    conv_w_body(W1, w1_hi, w1_lo, DIM, 4 * DIM, (blk - 2048) * 256 + threadIdx.x);
  }
}

// standalone conversion (W2, staged after Wo GEMM frees its units)
__global__ __launch_bounds__(256) void conv_w_kernel(
    const float* __restrict__ W, ushort_t* __restrict__ hi, ushort_t* __restrict__ lo,
    int K, int N) {
  conv_w_body(W, hi, lo, K, N, blockIdx.x * 256 + threadIdx.x);
}

// ---------------- LN chain device body: x row (fp32 regs) -> tiled hi/lo planes -------
__device__ __forceinline__ void ln_chain_body(
    const float xv[4], int row, double cc,
    const float* __restrict__ gamma, const float* __restrict__ beta,
    ushort_t* __restrict__ ohi, ushort_t* __restrict__ olo,
    double sh[3][4], int t) {
  double s0 = 0.0, s1 = 0.0;
#pragma unroll
  for (int i = 0; i < 4; i++) {
    s0 += (double)xv[i];
    s1 += (double)xv[i] * (double)xv[i];
  }
  s0 = wsum64(s0); s1 = wsum64(s1);
  const int wid = t >> 6, lane = t & 63;
  __syncthreads();
  if (lane == 0) { sh[0][wid] = s0; sh[1][wid] = s1; }
  __syncthreads();
  s0 = sh[0][0] + sh[0][1] + sh[0][2] + sh[0][3];
  s1 = sh[1][0] + sh[1][1] + sh[1][2] + sh[1][3];

  const double sqc = fmax(sqrt(cc), D_EPS);
  const double xn  = sqrt(s1);
  double a = 0.0;
  if (xn >= D_EPS) a = atanh(fmin(xn, 1.0 - D_EPS)) / sqc / fmax(xn, D_EPS);
  const double mu   = a * s0 / (double)DIM;
  const double var  = a * a * s1 / (double)DIM - mu * mu;
  const double invs = 1.0 / sqrt(var + 1e-6);

  double tv[4]; double s2 = 0.0;
#pragma unroll
  for (int i = 0; i < 4; i++) {
    const int col = t + 256 * i;
    tv[i] = (a * (double)xv[i] - mu) * invs * (double)gamma[col] + (double)beta[col];
    s2 += tv[i] * tv[i];
  }
  s2 = wsum64(s2);
  __syncthreads();
  if (lane == 0) sh[0][wid] = s2;
  __syncthreads();
  s2 = sh[0][0] + sh[0][1] + sh[0][2] + sh[0][3];

  const double tn = sqrt(s2);
  double C = 0.0;
  if (tn >= D_EPS) {
    const double safe_t = fmax(tn, D_EPS);
    const double mag2 = tanh(sqc * safe_t) / sqc;   // expmap0 magnitude
    const double en = mag2 * (tn / safe_t);         // ||e|| analytic
    const double pn = fmax(en, D_EPS);
    const double f  = (pn >= 1.0) ? (1.0 - D_EPS) / pn : 1.0;   // project
    const double yn = en * f;
    if (yn >= D_EPS) {
      const double mag3 = atanh(fmin(yn, 1.0 - D_EPS)) / sqc;   // logmap0
      C = (mag2 / safe_t) * f * (mag3 / fmax(yn, D_EPS));
    }
  }
#pragma unroll
  for (int i = 0; i < 4; i++) {
    const int col = t + 256 * i;
    store_hl(ohi, olo, tiled_addr(row, col, DIM), (float)(tv[i] * C));
  }
}

// ---------------- tangent-space layernorm chain kernel (LN1) ----------------
__global__ __launch_bounds__(256) void ln_tan_kernel(
    const float* __restrict__ xin, const float* __restrict__ cb,
    const float* __restrict__ gamma, const float* __restrict__ beta,
    ushort_t* __restrict__ ohi, ushort_t* __restrict__ olo) {
  __shared__ double sh[3][4];
  const int row = blockIdx.x;
  const int b = row / SEQ;
  const float* xr = xin + (size_t)row * DIM;
  const int t = threadIdx.x;
  float xv[4];
#pragma unroll
  for (int i = 0; i < 4; i++) xv[i] = xr[t + 256 * i];
  ln_chain_body(xv, row, (double)cb[b], gamma, beta, ohi, olo, sh, t);
}

// ------- mobius core: given row sums, produce Pd,Qd -------
__device__ __forceinline__ void mobius_coef(
    double sx2, double st2, double sxt, double cc, double& Pd, double& Qd) {
  const double sqc = fmax(sqrt(cc), D_EPS);
  const double tn = sqrt(st2);
  double s = 0.0;
  if (tn >= D_EPS) {
    const double safe = fmax(tn, D_EPS);
    const double mag = tanh(sqc * safe) / sqc;      // expmap0
    const double en = mag * (tn / safe);
    const double pn = fmax(en, D_EPS);
    const double f  = (pn >= 1.0) ? (1.0 - D_EPS) / pn : 1.0;  // project
    s = (mag / safe) * f;                            // y_i = s * t_i
  }
  const double x2 = sx2, y2 = s * s * st2, xy = s * sxt;
  const double P   = 1.0 + 2.0 * cc * xy + cc * y2;
  const double Q   = 1.0 - cc * x2;
  const double den = fmax(1.0 + 2.0 * cc * xy + cc * cc * x2 * y2, D_EPS);
  const double num2 = P * P * x2 + Q * Q * y2 + 2.0 * P * Q * xy;
  const double rn  = sqrt(fmax(num2, 0.0)) / den;
  const double pn2 = fmax(rn, D_EPS);
  const double pf  = (pn2 >= 1.0) ? (1.0 - D_EPS) / pn2 : 1.0;  // project
  Pd = (P / den) * pf;
  Qd = (Q / den) * pf * s;
}

// ------- out = mobius_add(xb, expmap0(p0+p1+p2+p3+bias, c), c) -------
// NOTE: may be called with out == xb (each thread reads its cols before writing).
__global__ __launch_bounds__(256) void expmobius_parts4_kernel(
    const float* __restrict__ xb,
    const float* __restrict__ p0, const float* __restrict__ p1,
    const float* __restrict__ p2, const float* __restrict__ p3,
    const float* __restrict__ bias, const float* __restrict__ cb,
    float* __restrict__ out) {
  __shared__ double sh[3][4];
  const int row = blockIdx.x;
  const int b = row / SEQ;
  const size_t ro = (size_t)row * DIM;
  const int t = threadIdx.x;
  float xv[4];
  double tv[4];
  double sx2 = 0.0, st2 = 0.0, sxt = 0.0;
#pragma unroll
  for (int i = 0; i < 4; i++) {
    const int col = t + 256 * i;
    xv[i] = xb[ro + col];
    tv[i] = (double)p0[ro + col] + (double)p1[ro + col] +
            (double)p2[ro + col] + (double)p3[ro + col] + (double)bias[col];
    sx2 += (double)xv[i] * (double)xv[i];
    st2 += tv[i] * tv[i];
    sxt += (double)xv[i] * tv[i];
  }
  sx2 = wsum64(sx2); st2 = wsum64(st2); sxt = wsum64(sxt);
  const int wid = t >> 6, lane = t & 63;
  if (lane == 0) { sh[0][wid] = sx2; sh[1][wid] = st2; sh[2][wid] = sxt; }
  __syncthreads();
  sx2 = sh[0][0] + sh[0][1] + sh[0][2] + sh[0][3];
  st2 = sh[1][0] + sh[1][1] + sh[1][2] + sh[1][3];
  sxt = sh[2][0] + sh[2][1] + sh[2][2] + sh[2][3];
  double Pd, Qd;
  mobius_coef(sx2, st2, sxt, (double)cb[b], Pd, Qd);
#pragma unroll
  for (int i = 0; i < 4; i++)
    out[ro + t + 256 * i] = (float)(Pd * (double)xv[i] + Qd * tv[i]);
}

// ------- fused: x_att = mobius_add(x, expmap0(parts+bias)); t2P = LN-chain(x_att) -------
__global__ __launch_bounds__(256) void expmobius_ln_kernel(
    const float* __restrict__ xb,
    const float* __restrict__ p0, const float* __restrict__ p1,
    const float* __restrict__ p2, const float* __restrict__ p3,
    const float* __restrict__ bias, const float* __restrict__ cb,
    const float* __restrict__ gamma, const float* __restrict__ beta,
    float* __restrict__ out, ushort_t* __restrict__ ohi, ushort_t* __restrict__ olo) {
  __shared__ double sh[3][4];
  const int row = blockIdx.x;
  const int b = row / SEQ;
  const size_t ro = (size_t)row * DIM;
  const int t = threadIdx.x;
  float xv[4];
  double tv[4];
  double sx2 = 0.0, st2 = 0.0, sxt = 0.0;
#pragma unroll
  for (int i = 0; i < 4; i++) {
    const int col = t + 256 * i;
    xv[i] = xb[ro + col];
    tv[i] = (double)p0[ro + col] + (double)p1[ro + col] +
            (double)p2[ro + col] + (double)p3[ro + col] + (double)bias[col];
    sx2 += (double)xv[i] * (double)xv[i];
    st2 += tv[i] * tv[i];
    sxt += (double)xv[i] * tv[i];
  }
  sx2 = wsum64(sx2); st2 = wsum64(st2); sxt = wsum64(sxt);
  const int wid = t >> 6, lane = t & 63;
  if (lane == 0) { sh[0][wid] = sx2; sh[1][wid] = st2; sh[2][wid] = sxt; }
  __syncthreads();
  sx2 = sh[0][0] + sh[0][1] + sh[0][2] + sh[0][3];
  st2 = sh[1][0] + sh[1][1] + sh[1][2] + sh[1][3];
  sxt = sh[2][0] + sh[2][1] + sh[2][2] + sh[2][3];
  const double cc = (double)cb[b];
  double Pd, Qd;
  mobius_coef(sx2, st2, sxt, cc, Pd, Qd);
  float ov[4];
#pragma unroll
  for (int i = 0; i < 4; i++) {
    ov[i] = (float)(Pd * (double)xv[i] + Qd * tv[i]);   // fp32-rounded x_att
    out[ro + t + 256 * i] = ov[i];
  }
  // LN2 chain on the fp32-rounded x_att (bit-matches the unfused two-kernel path)
  ln_chain_body(ov, row, cc, gamma, beta, ohi, olo, sh, t);
}

// ---------------- RoPE + expmap0 per head, in place on q and k ----------------
// Also emits per-(row,head) squared norms of the STORED fp32 outputs (fp64).
__global__ __launch_bounds__(256) void rope_expmap_kernel(
    float* __restrict__ q, float* __restrict__ k,
    const float* __restrict__ freqs, const float* __restrict__ cb,
    double* __restrict__ q2d, double* __restrict__ k2d) {
  const int row = blockIdx.x;           // b*SEQ + n
  const int b = row / SEQ, n = row % SEQ;
  const int t = threadIdx.x;
  const int h = t >> 4, j = t & 15;
  const int p1 = j, p2 = j + 16;        // pair indices in [0,32)
  const double f1 = (double)freqs[n * (DH / 2) + p1];
  const double f2 = (double)freqs[n * (DH / 2) + p2];
  const double c1 = cos(f1), s1 = sin(f1);
  const double c2 = cos(f2), s2 = sin(f2);
  const double cc  = (double)cb[b];
  const double sqc = fmax(sqrt(cc), D_EPS);
  const size_t base = (size_t)row * DIM + (size_t)h * DH;
  float* arrs[2] = {q, k};
  double* outs[2] = {q2d, k2d};
#pragma unroll
  for (int a = 0; a < 2; a++) {
    float* p = arrs[a] + base;
    const double xr1 = p[p1], xi1 = p[p1 + 32];
    const double xr2 = p[p2], xi2 = p[p2 + 32];
    const double r1 = xr1 * c1 - xi1 * s1, i1 = xr1 * s1 + xi1 * c1;
    const double r2 = xr2 * c2 - xi2 * s2, i2 = xr2 * s2 + xi2 * c2;
    double nrm2 = r1 * r1 + i1 * i1 + r2 * r2 + i2 * i2;
#pragma unroll
    for (int m = 8; m >= 1; m >>= 1) nrm2 += __shfl_xor(nrm2, m, 16);
    const double vn = sqrt(nrm2);
    double sc = 0.0;
    if (vn >= D_EPS) {
      const double safe = fmax(vn, D_EPS);
      const double mag = tanh(sqc * safe) / sqc;
      const double en = mag * (vn / safe);
      const double pn = fmax(en, D_EPS);
      const double f  = (pn >= 1.0) ? (1.0 - D_EPS) / pn : 1.0;
      sc = (mag / safe) * f;
    }
    const float o1 = (float)(r1 * sc), o2 = (float)(i1 * sc);
    const float o3 = (float)(r2 * sc), o4 = (float)(i2 * sc);
    p[p1] = o1; p[p1 + 32] = o2;
    p[p2] = o3; p[p2 + 32] = o4;
    // exact fp64 sum of squares of the STORED fp32 values
    double s2 = (double)o1 * o1 + (double)o2 * o2 + (double)o3 * o3 + (double)o4 * o4;
#pragma unroll
    for (int m = 8; m >= 1; m >>= 1) s2 += __shfl_xor(s2, m, 16);
    if (j == 0) outs[a][row * NH + h] = s2;
  }
}

// ---------------- sliding-window Poincare attention (tiled hi/lo output) ----------------
// Block = 8 consecutive queries of one (b,h). The shared 39-row K/V window is
// staged in LDS with coalesced loads (fixes across-lane L1 scatter of R9).
// Lane w of group g handles key n-31+w = LDS row g+w. Accumulation orders are
// byte-identical to the R9 kernel -> bit-identical output.
__global__ __launch_bounds__(256) void attn_kernel(
    const float* __restrict__ qh, const float* __restrict__ kh,
    const float* __restrict__ v, const float* __restrict__ cb,
    const float* __restrict__ geo,
    const double* __restrict__ q2d, const double* __restrict__ k2d,
    ushort_t* __restrict__ ohi, ushort_t* __restrict__ olo) {
  constexpr int RWS = 39;   // rows n0-31 .. n0+7
  constexpr int STR = 66;   // float stride (pad 64 -> 66; float2-aligned)
  __shared__ float Ks[RWS * STR];
  __shared__ float Vs[RWS * STR];
  __shared__ __align__(16) float qs[8][DH];
  const int t = threadIdx.x;
  const int g = t >> 5, w = t & 31;
  const int gid0 = blockIdx.x * 8;
  const int n0 = gid0 & (SEQ - 1);
  const int bh = gid0 >> 10;
  const int h = bh & (NH - 1);
  const int b = bh >> 4;
  const int n = n0 + g;
  const int row = b * SEQ + n;
  const size_t qbase = (size_t)row * DIM + (size_t)h * DH;
  qs[g][w] = qh[qbase + w];
  qs[g][w + 32] = qh[qbase + w + 32];
  // cooperative K/V window load: coalesced float2 rows, zero-filled OOB
  for (int idx = t; idx < RWS * 32; idx += 256) {
    const int r = idx >> 5, j = idx & 31;
    const int m = n0 - 31 + r;
    float2 kv = {0.f, 0.f}, vv = {0.f, 0.f};
    if (m >= 0) {
      const size_t base = ((size_t)(b * SEQ + m)) * DIM + (size_t)h * DH + 2 * j;
      kv = *(const float2*)(kh + base);
      vv = *(const float2*)(v + base);
    }
    *(float2*)&Ks[r * STR + 2 * j] = kv;
    *(float2*)&Vs[r * STR + 2 * j] = vv;
  }
  __syncthreads();

  const double cc  = (double)cb[b];
  const double sqc = fmax(sqrt(cc), D_EPS);
  const double a2 = q2d[row * NH + h];

  const int msrc = n - 31 + w;
  double y2 = 0.0, qy = 0.0;
  if (msrc >= 0) {
    y2 = k2d[(b * SEQ + msrc) * NH + h];
    const float* kr = &Ks[(g + w) * STR];
    const float* qr = qs[g];
#pragma unroll
    for (int j = 0; j < 32; j++) {
      const float2 kv = *(const float2*)(kr + 2 * j);
      const float2 qv = *(const float2*)(qr + 2 * j);
      qy += (double)qv.x * (double)kv.x;
      qy += (double)qv.y * (double)kv.y;
    }
  }
  const double ay = -qy;  // mobius_add(-q, k)
  const double P = 1.0 + 2.0 * cc * ay + cc * y2;
  const double Q = 1.0 - cc * a2;
  const double den = fmax(1.0 + 2.0 * cc * ay + cc * cc * a2 * y2, D_EPS);
  const double num2 = P * P * a2 + Q * Q * y2 + 2.0 * P * Q * ay;
  const double rn = sqrt(fmax(num2, 0.0)) / den;
  const double pn = fmax(rn, D_EPS);
  const double addn = (pn >= 1.0) ? (1.0 - D_EPS) * (rn / pn) : rn;  // project
  const double arg = fmin(sqc * addn, 1.0 - D_EPS);
  const double dist = 2.0 * atanh(arg) / sqc;
  const double logit = -(double)geo[h] * dist;

  double mx = logit;
#pragma unroll
  for (int m = 16; m >= 1; m >>= 1) mx = fmax(mx, __shfl_xor(mx, m, 32));
  const double e = exp(logit - mx);
  double se = e;
#pragma unroll
  for (int m = 16; m >= 1; m >>= 1) se += __shfl_xor(se, m, 32);
  const double p = e / se;

  // PV: lane w accumulates output dims 2w, 2w+1 from the LDS V window
  double acc1 = 0.0, acc2 = 0.0;
  for (int wp = 0; wp < 32; wp++) {
    const double pw = __shfl(p, wp, 32);
    const int mp = n - 31 + wp;
    if (mp >= 0) {
      const float2 vv = *(const float2*)&Vs[(g + wp) * STR + 2 * w];
      acc1 += pw * (double)vv.x;
      acc2 += pw * (double)vv.y;
    }
  }
  const int col = h * DH + 2 * w;
  store_hl(ohi, olo, tiled_addr(row, col, DIM), (float)acc1);
  store_hl(ohi, olo, tiled_addr(row, col + 1, DIM), (float)acc2);
}

// ---------------- epilogue helper ----------------
__device__ __forceinline__ float gelu_tanh(float x) {
  const float x3 = x * x * x;
  return 0.5f * x * (1.0f + tanhf(0.7978845608028654f * (x + 0.044715f * x3)));
}

// ===== bf16x3 MFMA GEMM body: 128x128 tile, 256 thr (4 waves), BK=32 =====
// 16x16x32 MFMA, wave-tile 64x64. A,B: tiled hi/lo planes in fragment order.
// Staging via global_load_lds (m97 structure): zero staging VGPRs, no ds_writes.
// EPI: 0 = +bias fp32 out; 1 = +bias gelu tiled out; 2 = fp32 partial (no bias).
template <int EPI>
__device__ __forceinline__ void mfma_gemm_body(
    const ushort_t* __restrict__ Ahi, const ushort_t* __restrict__ Alo, int Kld,
    const ushort_t* __restrict__ Bhi, const ushort_t* __restrict__ Blo, int KB,
    const float* __restrict__ bias, float* __restrict__ Cf,
    ushort_t* __restrict__ Chi, ushort_t* __restrict__ Clo, int KldOut,
    int N, int k0, int klen, int m0, int n0) {
  __shared__ __align__(16) ushort_t AsH[4096], AsL[4096], BsH[4096], BsL[4096];
  const int t = threadIdx.x;
  const int lane = t & 63, wave = t >> 6;
  const int wm = (wave >> 1) << 6, wn = (wave & 1) << 6;   // 64x64 per wave
  const size_t abase = (size_t)(m0 >> 7) * (Kld >> 5) * 4096;
  const size_t bbase = (size_t)(n0 >> 7) * (KB >> 5) * 4096;

  float4v acc[4][4];
#pragma unroll
  for (int i = 0; i < 4; i++)
#pragma unroll
    for (int j = 0; j < 4; j++) acc[i][j] = (float4v){0.f, 0.f, 0.f, 0.f};

  for (int kt = 0; kt < klen; kt += 32) {
    const size_t at = abase + (size_t)((k0 + kt) >> 5) * 4096;
    const size_t bt = bbase + (size_t)((k0 + kt) >> 5) * 4096;
    __syncthreads();                   // prev compute done, LDS reusable
    // stage 4 plane-tiles of 8 KB: 2 rounds x (4 waves x 1 KB DMA) each
#pragma unroll
    for (int r = 0; r < 2; r++) {
      const int go = (r << 11) + (t << 3);          // per-lane ushort offset
      const int lo = (r << 11) + (wave << 9);       // wave-uniform LDS base
      GLOAD_LDS(Ahi + at + go, AsH + lo);
      GLOAD_LDS(Alo + at + go, AsL + lo);
      GLOAD_LDS(Bhi + bt + go, BsH + lo);
      GLOAD_LDS(Blo + bt + go, BsL + lo);
    }
    __syncthreads();                   // drains vmcnt: tile resident
    // compute: 48 MFMAs (bf16x3: HH + HL + LH)
    short8v aH[4], aL[4];
    const int ams = wm >> 4;
#pragma unroll
    for (int im = 0; im < 4; im++) {
      const int off = ((((ams + im) << 6) + lane) << 3);
      aH[im] = *(const short8v*)&AsH[off];
      aL[im] = *(const short8v*)&AsL[off];
    }
    const int bns = wn >> 4;
#pragma unroll
    for (int in_ = 0; in_ < 4; in_++) {
      const int off = ((((bns + in_) << 6) + lane) << 3);
      const short8v bH = *(const short8v*)&BsH[off];
      const short8v bL = *(const short8v*)&BsL[off];
#pragma unroll
      for (int im = 0; im < 4; im++) {
        acc[im][in_] = __builtin_amdgcn_mfma_f32_16x16x32_bf16(aH[im], bH, acc[im][in_], 0, 0, 0);
        acc[im][in_] = __builtin_amdgcn_mfma_f32_16x16x32_bf16(aH[im], bL, acc[im][in_], 0, 0, 0);
        acc[im][in_] = __builtin_amdgcn_mfma_f32_16x16x32_bf16(aL[im], bH, acc[im][in_], 0, 0, 0);
      }
    }
  }
  // epilogue: C/D layout col = lane&15, row = (lane>>4)*4 + r
  const int cq = lane >> 4, ci = lane & 15;
#pragma unroll
  for (int im = 0; im < 4; im++) {
    const int row = m0 + wm + im * 16 + cq * 4;
#pragma unroll
    for (int in_ = 0; in_ < 4; in_++) {
      const int col = n0 + wn + in_ * 16 + ci;
      if (EPI == 2) {
#pragma unroll
        for (int r = 0; r < 4; r++) Cf[(size_t)(row + r) * N + col] = acc[im][in_][r];
      } else if (EPI == 0) {
        const float bv_ = bias[col];
#pragma unroll
        for (int r = 0; r < 4; r++) Cf[(size_t)(row + r) * N + col] = acc[im][in_][r] + bv_;
      } else {
        const float bv_ = bias[col];
#pragma unroll
        for (int r = 0; r < 4; r++)
          store_hl(Chi, Clo, tiled_addr(row + r, col, KldOut),
                   gelu_tanh(acc[im][in_][r] + bv_));
      }
    }
  }
}

// fused QKV: blockIdx.x = which*8 + ntile
__global__ __launch_bounds__(256) void qkv_mfma(
    const ushort_t* __restrict__ Ahi, const ushort_t* __restrict__ Alo,
    const ushort_t* __restrict__ Whi, const ushort_t* __restrict__ Wlo,
    const float* __restrict__ bq, const float* __restrict__ bk, const float* __restrict__ bv,
    float* __restrict__ Cq, float* __restrict__ Ck, float* __restrict__ Cv) {
  const int which = blockIdx.x >> 3;
  const int n0 = (blockIdx.x & 7) << 7;
  const size_t woff = (size_t)which << 20;
  const float* bias = (which == 0) ? bq : (which == 1) ? bk : bv;
  float* C = (which == 0) ? Cq : (which == 1) ? Ck : Cv;
  mfma_gemm_body<0>(Ahi, Alo, DIM, Whi + woff, Wlo + woff, DIM, bias, C,
                    nullptr, nullptr, 0, DIM, 0, DIM, blockIdx.y << 7, n0);
}

// FFN up + gelu, tiled hi/lo hidden output
__global__ __launch_bounds__(256) void ffn_up_mfma(
    const ushort_t* __restrict__ Ahi, const ushort_t* __restrict__ Alo,
    const ushort_t* __restrict__ W1hi, const ushort_t* __restrict__ W1lo,
    const float* __restrict__ b1, ushort_t* __restrict__ Hhi, ushort_t* __restrict__ Hlo) {
  mfma_gemm_body<1>(Ahi, Alo, DIM, W1hi, W1lo, DIM, b1, nullptr, Hhi, Hlo, 4 * DIM,
                    4 * DIM, 0, DIM, blockIdx.y << 7, blockIdx.x << 7);
}

// split-K partial GEMM: blockIdx.z picks k-chunk and partial buffer
__global__ __launch_bounds__(256) void gemm_splitk_mfma(
    const ushort_t* __restrict__ Ahi, const ushort_t* __restrict__ Alo, int Kld,
    const ushort_t* __restrict__ Bhi, const ushort_t* __restrict__ Blo, int KB,
    float* __restrict__ C0, float* __restrict__ C1,
    float* __restrict__ C2, float* __restrict__ C3, int N, int klen) {
  const int z = blockIdx.z;
  float* C = (z == 0) ? C0 : (z == 1) ? C1 : (z == 2) ? C2 : C3;
  mfma_gemm_body<2>(Ahi, Alo, Kld, Bhi, Blo, KB, nullptr, C, nullptr, nullptr, 0,
                    N, z * klen, klen, blockIdx.y << 7, blockIdx.x << 7);
}

extern "C" void kernel_launch(void* const* d_in, const int* in_sizes, int n_in,
                              void* d_out, int out_size, void* d_ws, size_t ws_size,
                              hipStream_t stream) {
  const float* x     = (const float*)d_in[0];
  const float* freqs = (const float*)d_in[1];
  const float* c     = (const float*)d_in[2];
  const float* Wq = (const float*)d_in[3];  const float* bq = (const float*)d_in[4];
  const float* Wk = (const float*)d_in[5];  const float* bk = (const float*)d_in[6];
  const float* Wv = (const float*)d_in[7];  const float* bv = (const float*)d_in[8];
  const float* Wo = (const float*)d_in[9];  const float* bo = (const float*)d_in[10];
  const float* W1 = (const float*)d_in[11]; const float* b1 = (const float*)d_in[12];
  const float* W2 = (const float*)d_in[13]; const float* b2 = (const float*)d_in[14];
  const float* g1 = (const float*)d_in[15]; const float* be1 = (const float*)d_in[16];
  const float* g2 = (const float*)d_in[17]; const float* be2 = (const float*)d_in[18];
  const float* geo = (const float*)d_in[19];
  float* out = (float*)d_out;
  float* ws = (float*)d_ws;

  const size_t SZ = (size_t)ROWS * DIM;       // 2M floats per unit (8 MB) = 4M ushorts
  const size_t PL = SZ;                       // ushorts per activation plane (half unit)
  const uint32_t M1 = 1u << 20;               // ushorts per 1024x1024 weight plane
  auto us = [&](int i) { return (ushort_t*)(ws + (size_t)i * SZ); };

  // Unit plan (x_att lives in d_out) — audited R5 plan:
  // u0: x_tanP hi+lo  -> Wo part0 -> h1 hi (low half)
  // u1: qb            -> Wo part1 -> h1 hi (high half)
  // u2: kb            -> Wo part2 -> h1 lo (low half)
  // u3: vb            -> Wo part3 -> h1 lo (high half)
  // u4: attP hi+lo    -> t2P hi+lo -> FFN part0
  // u5: Wq/Wk/Wv/Wo hi planes -> W2 hi      u6: same, lo planes -> W2 lo
  // u7: W1 hi -> FFN part1    u8: W1 lo -> FFN part2
  // u9: q2/k2 norm tables (steps 3-4) -> FFN part3 (step 9+)
  ushort_t* xt_hi = us(0);           ushort_t* xt_lo = us(0) + PL;
  float* qb = ws + 1 * SZ; float* kb = ws + 2 * SZ; float* vb = ws + 3 * SZ;
  ushort_t* at_hi = us(4);           ushort_t* at_lo = us(4) + PL;
  ushort_t* qkvo_hi = us(5);         ushort_t* qkvo_lo = us(6);
  ushort_t* w1_hi = us(7);           ushort_t* w1_lo = us(8);
  ushort_t* w2_hi = us(5);           ushort_t* w2_lo = us(6);
  ushort_t* t2_hi = us(4);           ushort_t* t2_lo = us(4) + PL;
  ushort_t* h1_hi = us(0);           ushort_t* h1_lo = us(2);   // each spans 2 units
  double* q2d = (double*)(ws + 9 * SZ);        // ROWS*NH doubles (256 KB)
  double* k2d = q2d + (size_t)ROWS * NH;
  float* x_att = out;

  // 0. merged weight conversion (QKV+Wo -> u5/u6, W1 -> u7/u8)
  conv_all_kernel<<<4096, 256, 0, stream>>>(
      Wq, Wk, Wv, Wo, W1, qkvo_hi, qkvo_lo, w1_hi, w1_lo);
  // 1. tangent LN1 -> tiled planes (u0)
  ln_tan_kernel<<<ROWS, 256, 0, stream>>>(x, c, g1, be1, xt_hi, xt_lo);
  // 2. fused QKV (384 blocks)
  qkv_mfma<<<dim3(24, ROWS / 128), 256, 0, stream>>>(
      xt_hi, xt_lo, qkvo_hi, qkvo_lo, bq, bk, bv, qb, kb, vb);
  // 3. RoPE + expmap0 (q,k in place) + norm tables -> u9
  rope_expmap_kernel<<<ROWS, 256, 0, stream>>>(qb, kb, freqs, c, q2d, k2d);
  // 4. sliding-window Poincare attention -> tiled planes (u4)
  attn_kernel<<<WB * NH * SEQ / 8, 256, 0, stream>>>(
      qb, kb, vb, c, geo, q2d, k2d, at_hi, at_lo);
  // 5. output projection, split-K=4 -> partials u0..u3 (klen=256)
  gemm_splitk_mfma<<<dim3(DIM / 128, ROWS / 128, 4), 256, 0, stream>>>(
      at_hi, at_lo, DIM, qkvo_hi + 3 * M1, qkvo_lo + 3 * M1, DIM,
      ws + 0 * SZ, ws + 1 * SZ, ws + 2 * SZ, ws + 3 * SZ, DIM, DIM / 4);
  // 5b. W2 conversion into freed u5/u6
  conv_w_kernel<<<2048, 256, 0, stream>>>(W2, w2_hi, w2_lo, 4 * DIM, DIM);
  // 6+7. fused: x_att = mobius(...), t2P = LN2-chain(x_att) -> u4
  expmobius_ln_kernel<<<ROWS, 256, 0, stream>>>(
      x, ws + 0 * SZ, ws + 1 * SZ, ws + 2 * SZ, ws + 3 * SZ, bo, c,
      g2, be2, x_att, t2_hi, t2_lo);
  // 8. FFN up + gelu -> tiled hidden planes (u0-u3)
  ffn_up_mfma<<<dim3(4 * DIM / 128, ROWS / 128), 256, 0, stream>>>(
      t2_hi, t2_lo, w1_hi, w1_lo, b1, h1_hi, h1_lo);
  // 9. FFN down, split-K=4 -> partials u4,u7,u8,u9 (klen=1024; u9 norm tables dead)
  gemm_splitk_mfma<<<dim3(DIM / 128, ROWS / 128, 4), 256, 0, stream>>>(
      h1_hi, h1_lo, 4 * DIM, w2_hi, w2_lo, 4 * DIM,
      ws + 4 * SZ, ws + 7 * SZ, ws + 8 * SZ, ws + 9 * SZ, DIM, DIM);
  // 10. out = mobius_add(x_att, expmap0(sum(partials)+b2))  [out == x_att: safe]
  expmobius_parts4_kernel<<<ROWS, 256, 0, stream>>>(
      x_att, ws + 4 * SZ, ws + 7 * SZ, ws + 8 * SZ, ws + 9 * SZ, b2, c, out);
  (void)in_sizes; (void)n_in; (void)out_size; (void)ws_size;
}